// Round 10
// baseline (181.177 us; speedup 1.0000x reference)
//
#include <hip/hip_runtime.h>
#include <math.h>

#define BS 4
#define NTOK 196
#define DCH 384
#define HD 6144
#define ROWS (BS*NTOK)          // 784
#define MPAD 896                // 7*128
#define SCALE 0.05103103630798287f  // 1/sqrt(384)

typedef unsigned short u16;
typedef __attribute__((ext_vector_type(8))) short bf8v;      // 8 bf16 (4 VGPR)
typedef __attribute__((ext_vector_type(4))) float f4v;
typedef __attribute__((ext_vector_type(16))) float f16v;
typedef __attribute__((ext_vector_type(8))) unsigned short u16x8;
typedef __attribute__((ext_vector_type(4))) unsigned short u16x4;
typedef __attribute__((ext_vector_type(2))) unsigned int u32x2;

static __device__ __forceinline__ float b2f(u16 u) {
    unsigned int x = ((unsigned int)u) << 16;
    float f; __builtin_memcpy(&f, &x, 4); return f;
}
static __device__ __forceinline__ u16 f2b(float f) {
    unsigned int x; __builtin_memcpy(&x, &f, 4);
    unsigned int r = x + 0x7FFF + ((x >> 16) & 1);
    return (u16)(r >> 16);
}
static __device__ __forceinline__ unsigned int pack2(float lo, float hi) {
    unsigned int r;
    asm("v_cvt_pk_bf16_f32 %0, %1, %2" : "=v"(r) : "v"(lo), "v"(hi));
    return r;
}
static __device__ __forceinline__ float blo(unsigned int u) {
    unsigned int x = u << 16; float f; __builtin_memcpy(&f, &x, 4); return f;
}
static __device__ __forceinline__ float bhi(unsigned int u) {
    unsigned int x = u & 0xffff0000u; float f; __builtin_memcpy(&f, &x, 4); return f;
}

// ---------------------------------------------------------------- LayerNorm (f32 + bf16 out, pad to 896)
__global__ __launch_bounds__(128) void ln_kernel(
    const float* __restrict__ x, const float* __restrict__ gamma,
    const float* __restrict__ beta, float* __restrict__ xn, u16* __restrict__ xnb)
{
    int row = blockIdx.x;
    int t = threadIdx.x;
    if (row >= ROWS) {
        xnb[(size_t)row*DCH + t] = 0;
        xnb[(size_t)row*DCH + t + 128] = 0;
        xnb[(size_t)row*DCH + t + 256] = 0;
        return;
    }
    const float* xr = x + (size_t)row * DCH;
    float v0 = xr[t], v1 = xr[t + 128], v2 = xr[t + 256];
    float s  = v0 + v1 + v2;
    float ss = v0*v0 + v1*v1 + v2*v2;
    #pragma unroll
    for (int off = 1; off < 64; off <<= 1) {
        s  += __shfl_xor(s,  off);
        ss += __shfl_xor(ss, off);
    }
    __shared__ float red[4];
    int wv = t >> 6;
    if ((t & 63) == 0) { red[wv*2] = s; red[wv*2+1] = ss; }
    __syncthreads();
    float S = red[0] + red[2], SS = red[1] + red[3];
    float mu  = S * (1.0f / DCH);
    float var = SS * (1.0f / DCH) - mu * mu;
    float inv = rsqrtf(var + 1e-5f);
    float* xo = xn + (size_t)row * DCH;
    u16*   xb = xnb + (size_t)row * DCH;
    float r0 = (v0 - mu) * inv * gamma[t]       + beta[t];
    float r1 = (v1 - mu) * inv * gamma[t + 128] + beta[t + 128];
    float r2 = (v2 - mu) * inv * gamma[t + 256] + beta[t + 256];
    xo[t] = r0; xo[t+128] = r1; xo[t+256] = r2;
    xb[t] = f2b(r0); xb[t+128] = f2b(r1); xb[t+256] = f2b(r2);
}

// ------------------------------------------------- W[384][6144] -> Wb[n][k] bf16 (k-contiguous)
__global__ __launch_bounds__(256) void convert_w_kernel(
    const float* __restrict__ Wq, const float* __restrict__ Wk, const float* __restrict__ Wv,
    u16* __restrict__ Wqb, u16* __restrict__ Wkb, u16* __restrict__ Wvb)
{
    const float* W = (blockIdx.z == 0) ? Wq : (blockIdx.z == 1) ? Wk : Wv;
    u16* Wb        = (blockIdx.z == 0) ? Wqb : (blockIdx.z == 1) ? Wkb : Wvb;
    __shared__ u16 tbuf[32][33];
    int tid = threadIdx.x;
    int k0 = blockIdx.y * 32, n0 = blockIdx.x * 32;
    #pragma unroll
    for (int it = 0; it < 4; it++) {
        int e = it*256 + tid; int kk = e >> 5, nn = e & 31;
        tbuf[kk][nn] = f2b(W[(size_t)(k0+kk)*HD + n0 + nn]);
    }
    __syncthreads();
    #pragma unroll
    for (int it = 0; it < 4; it++) {
        int e = it*256 + tid; int nn = e >> 5, kk = e & 31;
        Wb[(size_t)(n0+nn)*DCH + k0 + kk] = tbuf[kk][nn];
    }
}

// ------------------------------------------------- Wout[6144][384] -> Woutb[n][k] bf16, k=dc*16+h
__global__ __launch_bounds__(256) void convert_wout_kernel(
    const float* __restrict__ Wout, u16* __restrict__ Woutb)
{
    __shared__ u16 tbuf[128][65];
    int tid = threadIdx.x;
    int dc0 = blockIdx.x * 8;
    int n0  = blockIdx.y * 64;
    #pragma unroll
    for (int it = 0; it < 32; it++) {
        int e = it*256 + tid; int r = e >> 6, c = e & 63;
        int h = r >> 3, d = r & 7;
        tbuf[r][c] = f2b(Wout[(size_t)(h*DCH + dc0 + d)*DCH + n0 + c]);
    }
    __syncthreads();
    #pragma unroll
    for (int it = 0; it < 32; it++) {
        int e = it*256 + tid; int n = e >> 7, kk = e & 127;
        Woutb[(size_t)(n0+n)*HD + dc0*16 + kk] = tbuf[(kk & 15)*8 + (kk >> 4)][n];
    }
}

// ------------------------------------------------- MFMA proj GEMM (reg-staged) -> q/k [bd][i][h], v [bd][h][j]
__global__ __launch_bounds__(256) void gemm_qkv(
    const u16* __restrict__ xnb,
    const u16* __restrict__ Wqb, const u16* __restrict__ Wkb, const u16* __restrict__ Wvb,
    u16* __restrict__ qt, u16* __restrict__ kt, u16* __restrict__ vt)
{
    const u16* Wb = (blockIdx.z == 0) ? Wqb : (blockIdx.z == 1) ? Wkb : Wvb;
    u16* C        = (blockIdx.z == 0) ? qt : (blockIdx.z == 1) ? kt : vt;
    __shared__ u16 As[128*64];
    __shared__ u16 Bs[128*64];
    int tid = threadIdx.x, lane = tid & 63, wv = tid >> 6;
    int wm = wv >> 1, wn = wv & 1;
    int row0 = blockIdx.y * 128, col0 = blockIdx.x * 128;
    f4v acc[4][4] = {};
    int rsub = tid >> 3;
    int g8 = tid & 7;
    int g8s = g8 ^ (rsub & 7);

    for (int k0 = 0; k0 < 384; k0 += 64) {
        u16x8 ra[4], rb[4];
        #pragma unroll
        for (int c = 0; c < 4; c++) {
            int row = c*32 + rsub;
            ra[c] = *(const u16x8*)(xnb + (size_t)(row0+row)*DCH + k0 + g8*8);
            rb[c] = *(const u16x8*)(Wb  + (size_t)(col0+row)*DCH + k0 + g8*8);
        }
        __syncthreads();
        #pragma unroll
        for (int c = 0; c < 4; c++) {
            int row = c*32 + rsub;
            *(u16x8*)&As[row*64 + g8s*8] = ra[c];
            *(u16x8*)&Bs[row*64 + g8s*8] = rb[c];
        }
        __syncthreads();
        #pragma unroll
        for (int ks = 0; ks < 2; ks++) {
            int gr = (ks*4 + (lane >> 4)) ^ (lane & 7);
            bf8v af[4], bf[4];
            #pragma unroll
            for (int m = 0; m < 4; m++)
                af[m] = *(const bf8v*)&As[(wm*64 + m*16 + (lane & 15))*64 + gr*8];
            #pragma unroll
            for (int n = 0; n < 4; n++)
                bf[n] = *(const bf8v*)&Bs[(wn*64 + n*16 + (lane & 15))*64 + gr*8];
            #pragma unroll
            for (int m = 0; m < 4; m++)
                #pragma unroll
                for (int n = 0; n < 4; n++)
                    acc[m][n] = __builtin_amdgcn_mfma_f32_16x16x32_bf16(af[m], bf[n], acc[m][n], 0, 0, 0);
        }
    }
    int cb = lane & 15, rg = lane >> 4;
    #pragma unroll
    for (int m = 0; m < 4; m++) {
        int r0 = row0 + wm*64 + m*16 + rg*4;
        if (r0 >= ROWS) continue;
        int b = r0 / NTOK, i = r0 - b*NTOK;
        #pragma unroll
        for (int n = 0; n < 4; n++) {
            int ncol = col0 + wn*64 + n*16 + cb;
            int h = ncol / DCH, dc = ncol - h*DCH;
            if (blockIdx.z == 2) {
                size_t addr = ((size_t)((b*DCH + dc)*16 + h))*NTOK + i;
                u16x4 o = {f2b(acc[m][n][0]), f2b(acc[m][n][1]), f2b(acc[m][n][2]), f2b(acc[m][n][3])};
                *(u16x4*)(C + addr) = o;
            } else {
                size_t a2 = ((size_t)(b*DCH + dc))*(NTOK*16) + (size_t)i*16 + h;
                C[a2]      = f2b(acc[m][n][0]);
                C[a2 + 16] = f2b(acc[m][n][1]);
                C[a2 + 32] = f2b(acc[m][n][2]);
                C[a2 + 48] = f2b(acc[m][n][3]);
            }
        }
    }
}

// ------------------------------------------------- MFMA attention v4 (v3 math, 4-wave blocks)
// grid (bd, 2); wave = 32-row i-tile, it = by*4+wv, 8th wave idles.
__global__ __launch_bounds__(256) void attn_kernel(
    const u16* __restrict__ qt, const u16* __restrict__ kt, const u16* __restrict__ vt,
    float* __restrict__ probs, u16* __restrict__ ot2)
{
    __shared__ u16 Plds[4][2048];   // per-wave: 32 rows x 64 bf16 (128B row), swizzled
    int bd = blockIdx.x;
    int b = bd / DCH, dc = bd - b*DCH;
    int tid = threadIdx.x;
    int it = blockIdx.y*4 + (tid >> 6);
    if (it >= 7) return;            // wave-uniform early exit (no __syncthreads in kernel)
    int lane = tid & 63;
    int l31 = lane & 31, hi = lane >> 5;
    const u16* qb = qt + (size_t)bd * (NTOK*16);
    const u16* kb = kt + (size_t)bd * (NTOK*16);
    const u16* vb = vt + (size_t)bd * (NTOK*16);
    u16* Pw = Plds[tid >> 6];

    int iq = it*32 + l31;
    int iqc = iq < NTOK ? iq : NTOK-1;
    bf8v qf = *(const bf8v*)(qb + iqc*16 + hi*8);

    unsigned int P[6][8];     // 6 j-tiles x 16 bf16 (unnormalized exp), static-indexed
    float et[4];              // jt=6 tail (valid on hi==0)
    float s0 = 0.f, s1 = 0.f, s2 = 0.f, s3 = 0.f;

    #pragma unroll
    for (int jt = 0; jt < 7; jt++) {
        int j = jt*32 + l31;
        int jc = j < NTOK ? j : NTOK-1;
        bf8v kf = *(const bf8v*)(kb + jc*16 + hi*8);
        f16v z = {};
        f16v Sv = __builtin_amdgcn_mfma_f32_32x32x16_bf16(kf, qf, z, 0, 0, 0);
        if (jt < 6) {
            float e[16];
            #pragma unroll
            for (int r = 0; r < 16; r++) e[r] = __expf(Sv[r] * SCALE);
            #pragma unroll
            for (int r = 0; r < 16; r += 4) {
                s0 += e[r]; s1 += e[r+1]; s2 += e[r+2]; s3 += e[r+3];
            }
            #pragma unroll
            for (int g = 0; g < 4; g++) {
                P[jt][2*g]   = pack2(e[4*g],   e[4*g+1]);
                P[jt][2*g+1] = pack2(e[4*g+2], e[4*g+3]);
            }
        } else {
            #pragma unroll
            for (int r = 0; r < 4; r++)
                et[r] = (hi == 0) ? __expf(Sv[r] * SCALE) : 0.f;
            s0 += et[0]; s1 += et[1]; s2 += et[2]; s3 += et[3];
        }
    }
    float Sig = (s0 + s1) + (s2 + s3);
    Sig += __shfl_xor(Sig, 32);          // combine the row's two halves
    float inv = 1.0f / Sig;              // per-row (row = l31) normalizer

    float* prow_base = probs + (size_t)bd * NTOK * NTOK;
    f16v O = {};
    int row_lo = lane >> 4;      // 0..3 (probs store sublane)
    int scol   = lane & 15;      // 8B-chunk / 4-float column

    #pragma unroll
    for (int jtp = 0; jtp < 3; jtp++) {
        // ---- write this 64-j slab into the swizzled LDS tile (raw packed bf16)
        #pragma unroll
        for (int jtl = 0; jtl < 2; jtl++) {
            int jt = jtp*2 + jtl;
            #pragma unroll
            for (int g = 0; g < 4; g++) {
                int cs  = jtl*8 + 2*g + hi;              // 8B chunk 0..15
                int csw = cs ^ ((l31 & 7) << 1);         // even-mask XOR keeps 16B pairing
                u32x2 w2 = {P[jt][2*g], P[jt][2*g+1]};
                *(u32x2*)&Pw[l31*64 + csw*4] = w2;
            }
        }
        // ---- coalesced probs stores: 4 rows x 64 consecutive floats per instr
        #pragma unroll
        for (int rr = 0; rr < 8; rr++) {
            int row = rr*4 + row_lo;
            float rinv = __shfl(inv, row);               // all lanes active here
            int csw = scol ^ ((row & 7) << 1);
            u32x2 pv = *(const u32x2*)&Pw[row*64 + csw*4];
            int gi = it*32 + row;
            if (gi < NTOK) {
                f4v o = {blo(pv.x)*rinv, bhi(pv.x)*rinv, blo(pv.y)*rinv, bhi(pv.y)*rinv};
                *(f4v*)(prow_base + (size_t)gi*NTOK + jtp*64 + scol*4) = o;
            }
        }
        // ---- PV: A-frag = straight b128 read from the tile (row=l31, 8 consecutive j)
        #pragma unroll
        for (int jtl = 0; jtl < 2; jtl++) {
            #pragma unroll
            for (int u = 0; u < 2; u++) {
                int m  = jtl*4 + u*2 + hi;               // 16B chunk 0..7
                int mw = m ^ (l31 & 7);
                bf8v pf = *(const bf8v*)&Pw[l31*64 + mw*8];
                int j0 = jtp*64 + jtl*32 + u*16 + hi*8;
                int off = (l31 & 15)*NTOK + j0;
                u16x4 vlo = *(const u16x4*)(vb + off);
                u16x4 vh4 = *(const u16x4*)(vb + off + 4);
                u16 varr[8];
                #pragma unroll
                for (int e = 0; e < 4; e++) { varr[e] = vlo[e]; varr[4+e] = vh4[e]; }
                bf8v vf; __builtin_memcpy(&vf, varr, 16);
                O = __builtin_amdgcn_mfma_f32_32x32x16_bf16(pf, vf, O, 0, 0, 0);
            }
        }
    }

    // ---- tail jt=6 (j 192..195): probs + PV (frag is lane-local, no shfl)
    if (hi == 0 && iq < NTOK) {
        f4v o = {et[0]*inv, et[1]*inv, et[2]*inv, et[3]*inv};
        *(f4v*)(prow_base + (size_t)iq*NTOK + 192) = o;
    }
    {
        u16 arr[8];
        #pragma unroll
        for (int e = 0; e < 4; e++) {
            arr[e]   = (hi == 0) ? f2b(et[e]) : (u16)0;
            arr[4+e] = 0;
        }
        bf8v pf; __builtin_memcpy(&pf, arr, 16);
        int j0 = 192 + hi*8;
        int off = (l31 & 15)*NTOK + j0;    // may read a few u16 past this bd's v (x0 elems) — benign
        u16x4 vlo = *(const u16x4*)(vb + off);
        u16x4 vh4 = *(const u16x4*)(vb + off + 4);
        u16 varr[8];
        #pragma unroll
        for (int e = 0; e < 4; e++) { varr[e] = vlo[e]; varr[4+e] = vh4[e]; }
        bf8v vf; __builtin_memcpy(&vf, varr, 16);
        O = __builtin_amdgcn_mfma_f32_32x32x16_bf16(pf, vf, O, 0, 0, 0);
    }

    // ---- scale O by each row's inv (shfl BEFORE the store guard: all lanes active)
    float sc[16];
    #pragma unroll
    for (int r = 0; r < 16; r++) {
        int il = (r & 3) + 8*(r >> 2) + 4*hi;
        sc[r] = __shfl(inv, il);
    }
    if (l31 < 16) {
        #pragma unroll
        for (int r = 0; r < 16; r++) {
            int i = it*32 + (r & 3) + 8*(r >> 2) + 4*hi;
            if (i < NTOK)
                ot2[((size_t)(b*NTOK + i))*HD + dc*16 + l31] = f2b(O[r] * sc[r]);
        }
    }
}

// ------------------------------------------------- MFMA out-proj (reg-staged), split-K 24
__global__ __launch_bounds__(256) void gemm_wout(
    const u16* __restrict__ A, const u16* __restrict__ Bw, float* __restrict__ partial)
{
    __shared__ u16 As[128*64];
    __shared__ u16 Bs[128*64];
    int tid = threadIdx.x, lane = tid & 63, wv = tid >> 6;
    int wm = wv >> 1, wn = wv & 1;
    int row0 = blockIdx.y * 128, col0 = blockIdx.x * 128;
    int kbase = blockIdx.z * 256;
    f4v acc[4][4] = {};
    int rsub = tid >> 3;
    int g8 = tid & 7;
    int g8s = g8 ^ (rsub & 7);

    for (int k0 = kbase; k0 < kbase + 256; k0 += 64) {
        u16x8 ra[4], rb[4];
        #pragma unroll
        for (int c = 0; c < 4; c++) {
            int row = c*32 + rsub;
            int arow = row0 + row; if (arow > ROWS-1) arow = ROWS-1;   // clamp (masked at store)
            ra[c] = *(const u16x8*)(A  + (size_t)arow*HD + k0 + g8*8);
            rb[c] = *(const u16x8*)(Bw + (size_t)(col0+row)*HD + k0 + g8*8);
        }
        __syncthreads();
        #pragma unroll
        for (int c = 0; c < 4; c++) {
            int row = c*32 + rsub;
            *(u16x8*)&As[row*64 + g8s*8] = ra[c];
            *(u16x8*)&Bs[row*64 + g8s*8] = rb[c];
        }
        __syncthreads();
        #pragma unroll
        for (int ks = 0; ks < 2; ks++) {
            int gr = (ks*4 + (lane >> 4)) ^ (lane & 7);
            bf8v af[4], bf[4];
            #pragma unroll
            for (int m = 0; m < 4; m++)
                af[m] = *(const bf8v*)&As[(wm*64 + m*16 + (lane & 15))*64 + gr*8];
            #pragma unroll
            for (int n = 0; n < 4; n++)
                bf[n] = *(const bf8v*)&Bs[(wn*64 + n*16 + (lane & 15))*64 + gr*8];
            #pragma unroll
            for (int m = 0; m < 4; m++)
                #pragma unroll
                for (int n = 0; n < 4; n++)
                    acc[m][n] = __builtin_amdgcn_mfma_f32_16x16x32_bf16(af[m], bf[n], acc[m][n], 0, 0, 0);
        }
    }
    float* Pp = partial + (size_t)blockIdx.z * ROWS * DCH;
    int cb = lane & 15, rg = lane >> 4;
    #pragma unroll
    for (int m = 0; m < 4; m++) {
        int r0 = row0 + wm*64 + m*16 + rg*4;
        #pragma unroll
        for (int n = 0; n < 4; n++) {
            int ncol = col0 + wn*64 + n*16 + cb;
            #pragma unroll
            for (int j = 0; j < 4; j++) {
                int r = r0 + j;
                if (r < ROWS) Pp[(size_t)r*DCH + ncol] = acc[m][n][j];
            }
        }
    }
}

// ------------------------------------------------- split-K reduce + residual
__global__ __launch_bounds__(256) void reduce_out_kernel(
    const float* __restrict__ partial, const float* __restrict__ xn, float* __restrict__ out)
{
    int e = blockIdx.x * 256 + threadIdx.x;
    if (e < ROWS * DCH) {
        float s = xn[e];
        #pragma unroll
        for (int c = 0; c < 24; c++)
            s += partial[(size_t)c * ROWS * DCH + e];
        out[e] = s;
    }
}

extern "C" void kernel_launch(void* const* d_in, const int* in_sizes, int n_in,
                              void* d_out, int out_size, void* d_ws, size_t ws_size,
                              hipStream_t stream) {
    (void)in_sizes; (void)n_in; (void)out_size; (void)ws_size;
    const float* x     = (const float*)d_in[0];
    const float* Wq    = (const float*)d_in[1];
    const float* Wk    = (const float*)d_in[2];
    const float* Wv    = (const float*)d_in[3];
    const float* Wout  = (const float*)d_in[4];
    const float* gamma = (const float*)d_in[5];
    const float* beta  = (const float*)d_in[6];

    float* out   = (float*)d_out;
    float* probs = out + (size_t)ROWS * DCH;

    char* w = (char*)d_ws;
    float* xn  = (float*)w;  w += (size_t)ROWS*DCH*4;
    u16* xnb   = (u16*)w;    w += (size_t)MPAD*DCH*2;
    u16* Wqb   = (u16*)w;    w += (size_t)HD*DCH*2;
    u16* Wkb   = (u16*)w;    w += (size_t)HD*DCH*2;
    u16* Wvb   = (u16*)w;    w += (size_t)HD*DCH*2;
    u16* Woutb = (u16*)w;    w += (size_t)DCH*HD*2;
    u16* qt    = (u16*)w;    w += (size_t)ROWS*HD*2;
    u16* kt    = (u16*)w;    w += (size_t)ROWS*HD*2;
    u16* vt    = (u16*)w;    w += (size_t)ROWS*HD*2;
    u16* ot2   = (u16*)w;    w += (size_t)ROWS*HD*2;
    float* partial = (float*)qt;   // 24*1.2MB = 28.9MB spans qt+kt+vt exactly (all dead after attn)

    hipLaunchKernelGGL(ln_kernel, dim3(MPAD), dim3(128), 0, stream, x, gamma, beta, xn, xnb);
    hipLaunchKernelGGL(convert_w_kernel, dim3(192, 12, 3), dim3(256), 0, stream,
                       Wq, Wk, Wv, Wqb, Wkb, Wvb);
    hipLaunchKernelGGL(convert_wout_kernel, dim3(48, 6), dim3(256), 0, stream, Wout, Woutb);
    hipLaunchKernelGGL(gemm_qkv, dim3(48, 7, 3), dim3(256), 0, stream,
                       xnb, Wqb, Wkb, Wvb, qt, kt, vt);
    hipLaunchKernelGGL(attn_kernel, dim3(BS * DCH, 2), dim3(256), 0, stream,
                       qt, kt, vt, probs, ot2);
    hipLaunchKernelGGL(gemm_wout, dim3(3, 7, 24), dim3(256), 0, stream, ot2, Woutb, partial);
    hipLaunchKernelGGL(reduce_out_kernel, dim3((ROWS * DCH + 255) / 256), dim3(256), 0, stream,
                       partial, xn, out);
}

// Round 11
// 133.840 us; speedup vs baseline: 1.3537x; 1.3537x over previous
//
#include <hip/hip_runtime.h>
#include <math.h>

#define BS 4
#define NTOK 196
#define DCH 384
#define HD 6144
#define ROWS (BS*NTOK)          // 784
#define MPAD 896                // 7*128
#define SCALE 0.05103103630798287f  // 1/sqrt(384)

typedef unsigned short u16;
typedef __attribute__((ext_vector_type(8))) short bf8v;      // 8 bf16 (4 VGPR)
typedef __attribute__((ext_vector_type(4))) float f4v;
typedef __attribute__((ext_vector_type(16))) float f16v;
typedef __attribute__((ext_vector_type(8))) unsigned short u16x8;
typedef __attribute__((ext_vector_type(4))) unsigned short u16x4;
typedef __attribute__((ext_vector_type(2))) unsigned int u32x2;

static __device__ __forceinline__ float b2f(u16 u) {
    unsigned int x = ((unsigned int)u) << 16;
    float f; __builtin_memcpy(&f, &x, 4); return f;
}
static __device__ __forceinline__ u16 f2b(float f) {
    unsigned int x; __builtin_memcpy(&x, &f, 4);
    unsigned int r = x + 0x7FFF + ((x >> 16) & 1);
    return (u16)(r >> 16);
}
static __device__ __forceinline__ unsigned int pack2(float lo, float hi) {
    unsigned int r;
    asm("v_cvt_pk_bf16_f32 %0, %1, %2" : "=v"(r) : "v"(lo), "v"(hi));
    return r;
}
static __device__ __forceinline__ float blo(unsigned int u) {
    unsigned int x = u << 16; float f; __builtin_memcpy(&f, &x, 4); return f;
}
static __device__ __forceinline__ float bhi(unsigned int u) {
    unsigned int x = u & 0xffff0000u; float f; __builtin_memcpy(&f, &x, 4); return f;
}

// ---------------------------------------------------------------- LayerNorm (f32 + bf16 out, pad to 896)
__global__ __launch_bounds__(128) void ln_kernel(
    const float* __restrict__ x, const float* __restrict__ gamma,
    const float* __restrict__ beta, float* __restrict__ xn, u16* __restrict__ xnb)
{
    int row = blockIdx.x;
    int t = threadIdx.x;
    if (row >= ROWS) {
        xnb[(size_t)row*DCH + t] = 0;
        xnb[(size_t)row*DCH + t + 128] = 0;
        xnb[(size_t)row*DCH + t + 256] = 0;
        return;
    }
    const float* xr = x + (size_t)row * DCH;
    float v0 = xr[t], v1 = xr[t + 128], v2 = xr[t + 256];
    float s  = v0 + v1 + v2;
    float ss = v0*v0 + v1*v1 + v2*v2;
    #pragma unroll
    for (int off = 1; off < 64; off <<= 1) {
        s  += __shfl_xor(s,  off);
        ss += __shfl_xor(ss, off);
    }
    __shared__ float red[4];
    int wv = t >> 6;
    if ((t & 63) == 0) { red[wv*2] = s; red[wv*2+1] = ss; }
    __syncthreads();
    float S = red[0] + red[2], SS = red[1] + red[3];
    float mu  = S * (1.0f / DCH);
    float var = SS * (1.0f / DCH) - mu * mu;
    float inv = rsqrtf(var + 1e-5f);
    float* xo = xn + (size_t)row * DCH;
    u16*   xb = xnb + (size_t)row * DCH;
    float r0 = (v0 - mu) * inv * gamma[t]       + beta[t];
    float r1 = (v1 - mu) * inv * gamma[t + 128] + beta[t + 128];
    float r2 = (v2 - mu) * inv * gamma[t + 256] + beta[t + 256];
    xo[t] = r0; xo[t+128] = r1; xo[t+256] = r2;
    xb[t] = f2b(r0); xb[t+128] = f2b(r1); xb[t+256] = f2b(r2);
}

// ------------------------------------------------- W[384][6144] -> Wb[n'][k] bf16 (k-contiguous)
// q,k (z<2): n' = dc*16+h (permuted so a 16-col MFMA group = one bd); v (z==2): n' = n
__global__ __launch_bounds__(256) void convert_w_kernel(
    const float* __restrict__ Wq, const float* __restrict__ Wk, const float* __restrict__ Wv,
    u16* __restrict__ Wqb, u16* __restrict__ Wkb, u16* __restrict__ Wvb)
{
    const float* W = (blockIdx.z == 0) ? Wq : (blockIdx.z == 1) ? Wk : Wv;
    u16* Wb        = (blockIdx.z == 0) ? Wqb : (blockIdx.z == 1) ? Wkb : Wvb;
    __shared__ u16 tbuf[32][33];
    int tid = threadIdx.x;
    int k0 = blockIdx.y * 32, n0 = blockIdx.x * 32;
    #pragma unroll
    for (int it = 0; it < 4; it++) {
        int e = it*256 + tid; int kk = e >> 5, nn = e & 31;
        tbuf[kk][nn] = f2b(W[(size_t)(k0+kk)*HD + n0 + nn]);
    }
    __syncthreads();
    #pragma unroll
    for (int it = 0; it < 4; it++) {
        int e = it*256 + tid; int nn = e >> 5, kk = e & 31;
        int n_orig = n0 + nn;
        int np = (blockIdx.z == 2) ? n_orig : ((n_orig % DCH)*16 + n_orig / DCH);
        Wb[(size_t)np*DCH + k0 + kk] = tbuf[kk][nn];
    }
}

// ------------------------------------------------- Wout[6144][384] -> Woutb[n][k] bf16, k=dc*16+h
__global__ __launch_bounds__(256) void convert_wout_kernel(
    const float* __restrict__ Wout, u16* __restrict__ Woutb)
{
    __shared__ u16 tbuf[128][65];
    int tid = threadIdx.x;
    int dc0 = blockIdx.x * 8;
    int n0  = blockIdx.y * 64;
    #pragma unroll
    for (int it = 0; it < 32; it++) {
        int e = it*256 + tid; int r = e >> 6, c = e & 63;
        int h = r >> 3, d = r & 7;
        tbuf[r][c] = f2b(Wout[(size_t)(h*DCH + dc0 + d)*DCH + n0 + c]);
    }
    __syncthreads();
    #pragma unroll
    for (int it = 0; it < 32; it++) {
        int e = it*256 + tid; int n = e >> 7, kk = e & 127;
        Woutb[(size_t)(n0+n)*HD + dc0*16 + kk] = tbuf[(kk & 15)*8 + (kk >> 4)][n];
    }
}

// ------------------------------------------------- MFMA proj GEMM (reg-staged) -> q/k [bd][i*16+h], v [bd][h][j]
__global__ __launch_bounds__(256) void gemm_qkv(
    const u16* __restrict__ xnb,
    const u16* __restrict__ Wqb, const u16* __restrict__ Wkb, const u16* __restrict__ Wvb,
    u16* __restrict__ qt, u16* __restrict__ kt, u16* __restrict__ vt)
{
    const u16* Wb = (blockIdx.z == 0) ? Wqb : (blockIdx.z == 1) ? Wkb : Wvb;
    u16* C        = (blockIdx.z == 0) ? qt : (blockIdx.z == 1) ? kt : vt;
    __shared__ u16 As[128*64];
    __shared__ u16 Bs[128*64];
    int tid = threadIdx.x, lane = tid & 63, wv = tid >> 6;
    int wm = wv >> 1, wn = wv & 1;
    int row0 = blockIdx.y * 128, col0 = blockIdx.x * 128;
    f4v acc[4][4] = {};
    int rsub = tid >> 3;
    int g8 = tid & 7;
    int g8s = g8 ^ (rsub & 7);

    for (int k0 = 0; k0 < 384; k0 += 64) {
        u16x8 ra[4], rb[4];
        #pragma unroll
        for (int c = 0; c < 4; c++) {
            int row = c*32 + rsub;
            ra[c] = *(const u16x8*)(xnb + (size_t)(row0+row)*DCH + k0 + g8*8);
            rb[c] = *(const u16x8*)(Wb  + (size_t)(col0+row)*DCH + k0 + g8*8);
        }
        __syncthreads();
        #pragma unroll
        for (int c = 0; c < 4; c++) {
            int row = c*32 + rsub;
            *(u16x8*)&As[row*64 + g8s*8] = ra[c];
            *(u16x8*)&Bs[row*64 + g8s*8] = rb[c];
        }
        __syncthreads();
        #pragma unroll
        for (int ks = 0; ks < 2; ks++) {
            int gr = (ks*4 + (lane >> 4)) ^ (lane & 7);
            bf8v af[4], bf[4];
            #pragma unroll
            for (int m = 0; m < 4; m++)
                af[m] = *(const bf8v*)&As[(wm*64 + m*16 + (lane & 15))*64 + gr*8];
            #pragma unroll
            for (int n = 0; n < 4; n++)
                bf[n] = *(const bf8v*)&Bs[(wn*64 + n*16 + (lane & 15))*64 + gr*8];
            #pragma unroll
            for (int m = 0; m < 4; m++)
                #pragma unroll
                for (int n = 0; n < 4; n++)
                    acc[m][n] = __builtin_amdgcn_mfma_f32_16x16x32_bf16(af[m], bf[n], acc[m][n], 0, 0, 0);
        }
    }
    int cb = lane & 15, rg = lane >> 4;
    #pragma unroll
    for (int m = 0; m < 4; m++) {
        int r0 = row0 + wm*64 + m*16 + rg*4;
        if (r0 >= ROWS) continue;
        int b = r0 / NTOK, i = r0 - b*NTOK;
        #pragma unroll
        for (int n = 0; n < 4; n++) {
            int nb = col0 + wn*64 + n*16;
            if (blockIdx.z == 2) {
                int ncol = nb + cb;
                int h = ncol / DCH, dc = ncol - h*DCH;
                size_t addr = ((size_t)((b*DCH + dc)*16 + h))*NTOK + i;
                u16x4 o = {f2b(acc[m][n][0]), f2b(acc[m][n][1]), f2b(acc[m][n][2]), f2b(acc[m][n][3])};
                *(u16x4*)(C + addr) = o;
            } else {
                // permuted cols: n' = dc*16+h -> this 16-group is one bd, cb = h
                int dc = nb >> 4;
                size_t a2 = ((size_t)(b*DCH + dc))*(NTOK*16) + (size_t)i*16 + cb;
                C[a2]      = f2b(acc[m][n][0]);   // lanes cb=0..15: 32B dense
                C[a2 + 16] = f2b(acc[m][n][1]);
                C[a2 + 32] = f2b(acc[m][n][2]);
                C[a2 + 48] = f2b(acc[m][n][3]);
            }
        }
    }
}

// ------------------------------------------------- MFMA attention v5 (K/V staged in LDS, inv via LDS)
// grid (bd, 2); 256 thr; wave = 32-row i-tile, it = by*4+wv, 8th wave exits after barrier.
__global__ __launch_bounds__(256) void attn_kernel(
    const u16* __restrict__ qt, const u16* __restrict__ kt, const u16* __restrict__ vt,
    float* __restrict__ probs, u16* __restrict__ ot2)
{
    __shared__ u16 Klds[NTOK*16];        // [j][h], linear
    __shared__ u16 Vlds[NTOK*16 + 16];   // [h][j], +pad for tail b64 reads
    __shared__ u16 Plds[4][2048];        // per-wave 32x64 bf16, swizzled
    __shared__ float invs[4][32];        // per-wave row normalizers
    int bd = blockIdx.x;
    int b = bd / DCH, dc = bd - b*DCH;
    int tid = threadIdx.x;
    int wv = tid >> 6;
    int it = blockIdx.y*4 + wv;
    int lane = tid & 63;
    int l31 = lane & 31, hi = lane >> 5;
    const u16* qb = qt + (size_t)bd * (NTOK*16);
    const u16* kb = kt + (size_t)bd * (NTOK*16);
    const u16* vb = vt + (size_t)bd * (NTOK*16);

    // stage K and V once per block (coalesced; 4x dedup vs per-wave global loads)
    for (int e8 = tid; e8 < (NTOK*16)/8; e8 += 256) {
        *(u16x8*)&Klds[e8*8] = *(const u16x8*)(kb + e8*8);
        *(u16x8*)&Vlds[e8*8] = *(const u16x8*)(vb + e8*8);
    }
    __syncthreads();
    if (it >= 7) return;              // wave-uniform exit AFTER the only barrier
    u16* Pw = Plds[wv];

    int iq = it*32 + l31;
    int iqc = iq < NTOK ? iq : NTOK-1;
    bf8v qf = *(const bf8v*)(qb + iqc*16 + hi*8);

    unsigned int P[6][8];     // 6 j-tiles x 16 bf16 (unnormalized exp), static-indexed
    float et[4];              // jt=6 tail (valid on hi==0)
    float s0 = 0.f, s1 = 0.f, s2 = 0.f, s3 = 0.f;

    #pragma unroll
    for (int jt = 0; jt < 7; jt++) {
        int j = jt*32 + l31;
        int jc = j < NTOK ? j : NTOK-1;
        bf8v kf = *(const bf8v*)&Klds[jc*16 + hi*8];
        f16v z = {};
        f16v Sv = __builtin_amdgcn_mfma_f32_32x32x16_bf16(kf, qf, z, 0, 0, 0);
        if (jt < 6) {
            float e[16];
            #pragma unroll
            for (int r = 0; r < 16; r++) e[r] = __expf(Sv[r] * SCALE);
            #pragma unroll
            for (int r = 0; r < 16; r += 4) {
                s0 += e[r]; s1 += e[r+1]; s2 += e[r+2]; s3 += e[r+3];
            }
            #pragma unroll
            for (int g = 0; g < 4; g++) {
                P[jt][2*g]   = pack2(e[4*g],   e[4*g+1]);
                P[jt][2*g+1] = pack2(e[4*g+2], e[4*g+3]);
            }
        } else {
            #pragma unroll
            for (int r = 0; r < 4; r++)
                et[r] = (hi == 0) ? __expf(Sv[r] * SCALE) : 0.f;
            s0 += et[0]; s1 += et[1]; s2 += et[2]; s3 += et[3];
        }
    }
    float Sig = (s0 + s1) + (s2 + s3);
    Sig += __shfl_xor(Sig, 32);          // combine the row's two halves
    float inv = 1.0f / Sig;              // per-row (row = l31) normalizer
    if (hi == 0) invs[wv][l31] = inv;    // same-wave LDS broadcast (lgkmcnt-ordered)

    float* prow_base = probs + (size_t)bd * NTOK * NTOK;
    f16v O = {};
    int row_lo = lane >> 4;      // 0..3 (probs store sublane)
    int scol   = lane & 15;      // 8B-chunk / 4-float column

    #pragma unroll
    for (int jtp = 0; jtp < 3; jtp++) {
        // ---- write this 64-j slab into the swizzled LDS tile (raw packed bf16)
        #pragma unroll
        for (int jtl = 0; jtl < 2; jtl++) {
            int jt = jtp*2 + jtl;
            #pragma unroll
            for (int g = 0; g < 4; g++) {
                int cs  = jtl*8 + 2*g + hi;              // 8B chunk 0..15
                int csw = cs ^ ((l31 & 7) << 1);         // even-mask XOR keeps 16B pairing
                u32x2 w2 = {P[jt][2*g], P[jt][2*g+1]};
                *(u32x2*)&Pw[l31*64 + csw*4] = w2;
            }
        }
        // ---- coalesced probs stores: 4 rows x 64 consecutive floats per instr
        #pragma unroll
        for (int rr = 0; rr < 8; rr++) {
            int row = rr*4 + row_lo;
            float rinv = invs[wv][row];                  // LDS broadcast read
            int csw = scol ^ ((row & 7) << 1);
            u32x2 pv = *(const u32x2*)&Pw[row*64 + csw*4];
            int gi = it*32 + row;
            if (gi < NTOK) {
                f4v o = {blo(pv.x)*rinv, bhi(pv.x)*rinv, blo(pv.y)*rinv, bhi(pv.y)*rinv};
                *(f4v*)(prow_base + (size_t)gi*NTOK + jtp*64 + scol*4) = o;
            }
        }
        // ---- PV: A-frag = straight b128 read from the tile (row=l31, 8 consecutive j)
        #pragma unroll
        for (int jtl = 0; jtl < 2; jtl++) {
            #pragma unroll
            for (int u = 0; u < 2; u++) {
                int m  = jtl*4 + u*2 + hi;               // 16B chunk 0..7
                int mw = m ^ (l31 & 7);
                bf8v pf = *(const bf8v*)&Pw[l31*64 + mw*8];
                int j0 = jtp*64 + jtl*32 + u*16 + hi*8;
                int off = (l31 & 15)*NTOK + j0;
                u16x4 vlo = *(const u16x4*)&Vlds[off];
                u16x4 vh4 = *(const u16x4*)&Vlds[off + 4];
                u16 varr[8];
                #pragma unroll
                for (int e = 0; e < 4; e++) { varr[e] = vlo[e]; varr[4+e] = vh4[e]; }
                bf8v vf; __builtin_memcpy(&vf, varr, 16);
                O = __builtin_amdgcn_mfma_f32_32x32x16_bf16(pf, vf, O, 0, 0, 0);
            }
        }
    }

    // ---- tail jt=6 (j 192..195): probs + PV (frag is lane-local, no shfl)
    if (hi == 0 && iq < NTOK) {
        f4v o = {et[0]*inv, et[1]*inv, et[2]*inv, et[3]*inv};
        *(f4v*)(prow_base + (size_t)iq*NTOK + 192) = o;
    }
    {
        u16 arr[8];
        #pragma unroll
        for (int e = 0; e < 4; e++) {
            arr[e]   = (hi == 0) ? f2b(et[e]) : (u16)0;
            arr[4+e] = 0;
        }
        bf8v pf; __builtin_memcpy(&pf, arr, 16);
        int j0 = 192 + hi*8;
        int off = (l31 & 15)*NTOK + j0;    // hi=1 reads into pad (P=0) — benign
        u16x4 vlo = *(const u16x4*)&Vlds[off];
        u16x4 vh4 = *(const u16x4*)&Vlds[off + 4];
        u16 varr[8];
        #pragma unroll
        for (int e = 0; e < 4; e++) { varr[e] = vlo[e]; varr[4+e] = vh4[e]; }
        bf8v vf; __builtin_memcpy(&vf, varr, 16);
        O = __builtin_amdgcn_mfma_f32_32x32x16_bf16(pf, vf, O, 0, 0, 0);
    }

    // ---- scale O by each row's inv (LDS broadcast per D-row)
    if (l31 < 16) {
        #pragma unroll
        for (int r = 0; r < 16; r++) {
            int il = (r & 3) + 8*(r >> 2) + 4*hi;
            int i = it*32 + il;
            if (i < NTOK) {
                float iv = invs[wv][il];
                ot2[((size_t)(b*NTOK + i))*HD + dc*16 + l31] = f2b(O[r] * iv);
            }
        }
    }
}

// ------------------------------------------------- MFMA out-proj (reg-staged), split-K 24
__global__ __launch_bounds__(256) void gemm_wout(
    const u16* __restrict__ A, const u16* __restrict__ Bw, float* __restrict__ partial)
{
    __shared__ u16 As[128*64];
    __shared__ u16 Bs[128*64];
    int tid = threadIdx.x, lane = tid & 63, wv = tid >> 6;
    int wm = wv >> 1, wn = wv & 1;
    int row0 = blockIdx.y * 128, col0 = blockIdx.x * 128;
    int kbase = blockIdx.z * 256;
    f4v acc[4][4] = {};
    int rsub = tid >> 3;
    int g8 = tid & 7;
    int g8s = g8 ^ (rsub & 7);

    for (int k0 = kbase; k0 < kbase + 256; k0 += 64) {
        u16x8 ra[4], rb[4];
        #pragma unroll
        for (int c = 0; c < 4; c++) {
            int row = c*32 + rsub;
            int arow = row0 + row; if (arow > ROWS-1) arow = ROWS-1;   // clamp (masked at store)
            ra[c] = *(const u16x8*)(A  + (size_t)arow*HD + k0 + g8*8);
            rb[c] = *(const u16x8*)(Bw + (size_t)(col0+row)*HD + k0 + g8*8);
        }
        __syncthreads();
        #pragma unroll
        for (int c = 0; c < 4; c++) {
            int row = c*32 + rsub;
            *(u16x8*)&As[row*64 + g8s*8] = ra[c];
            *(u16x8*)&Bs[row*64 + g8s*8] = rb[c];
        }
        __syncthreads();
        #pragma unroll
        for (int ks = 0; ks < 2; ks++) {
            int gr = (ks*4 + (lane >> 4)) ^ (lane & 7);
            bf8v af[4], bf[4];
            #pragma unroll
            for (int m = 0; m < 4; m++)
                af[m] = *(const bf8v*)&As[(wm*64 + m*16 + (lane & 15))*64 + gr*8];
            #pragma unroll
            for (int n = 0; n < 4; n++)
                bf[n] = *(const bf8v*)&Bs[(wn*64 + n*16 + (lane & 15))*64 + gr*8];
            #pragma unroll
            for (int m = 0; m < 4; m++)
                #pragma unroll
                for (int n = 0; n < 4; n++)
                    acc[m][n] = __builtin_amdgcn_mfma_f32_16x16x32_bf16(af[m], bf[n], acc[m][n], 0, 0, 0);
        }
    }
    float* Pp = partial + (size_t)blockIdx.z * ROWS * DCH;
    int cb = lane & 15, rg = lane >> 4;
    #pragma unroll
    for (int m = 0; m < 4; m++) {
        int r0 = row0 + wm*64 + m*16 + rg*4;
        #pragma unroll
        for (int n = 0; n < 4; n++) {
            int ncol = col0 + wn*64 + n*16 + cb;
            #pragma unroll
            for (int j = 0; j < 4; j++) {
                int r = r0 + j;
                if (r < ROWS) Pp[(size_t)r*DCH + ncol] = acc[m][n][j];
            }
        }
    }
}

// ------------------------------------------------- split-K reduce + residual
__global__ __launch_bounds__(256) void reduce_out_kernel(
    const float* __restrict__ partial, const float* __restrict__ xn, float* __restrict__ out)
{
    int e = blockIdx.x * 256 + threadIdx.x;
    if (e < ROWS * DCH) {
        float s = xn[e];
        #pragma unroll
        for (int c = 0; c < 24; c++)
            s += partial[(size_t)c * ROWS * DCH + e];
        out[e] = s;
    }
}

extern "C" void kernel_launch(void* const* d_in, const int* in_sizes, int n_in,
                              void* d_out, int out_size, void* d_ws, size_t ws_size,
                              hipStream_t stream) {
    (void)in_sizes; (void)n_in; (void)out_size; (void)ws_size;
    const float* x     = (const float*)d_in[0];
    const float* Wq    = (const float*)d_in[1];
    const float* Wk    = (const float*)d_in[2];
    const float* Wv    = (const float*)d_in[3];
    const float* Wout  = (const float*)d_in[4];
    const float* gamma = (const float*)d_in[5];
    const float* beta  = (const float*)d_in[6];

    float* out   = (float*)d_out;
    float* probs = out + (size_t)ROWS * DCH;

    char* w = (char*)d_ws;
    float* xn  = (float*)w;  w += (size_t)ROWS*DCH*4;
    u16* xnb   = (u16*)w;    w += (size_t)MPAD*DCH*2;
    u16* Wqb   = (u16*)w;    w += (size_t)HD*DCH*2;
    u16* Wkb   = (u16*)w;    w += (size_t)HD*DCH*2;
    u16* Wvb   = (u16*)w;    w += (size_t)HD*DCH*2;
    u16* Woutb = (u16*)w;    w += (size_t)DCH*HD*2;
    u16* qt    = (u16*)w;    w += (size_t)ROWS*HD*2;
    u16* kt    = (u16*)w;    w += (size_t)ROWS*HD*2;
    u16* vt    = (u16*)w;    w += (size_t)ROWS*HD*2;
    u16* ot2   = (u16*)w;    w += (size_t)ROWS*HD*2;
    float* partial = (float*)qt;   // 24*1.2MB = 28.9MB spans qt+kt+vt (all dead after attn)

    hipLaunchKernelGGL(ln_kernel, dim3(MPAD), dim3(128), 0, stream, x, gamma, beta, xn, xnb);
    hipLaunchKernelGGL(convert_w_kernel, dim3(192, 12, 3), dim3(256), 0, stream,
                       Wq, Wk, Wv, Wqb, Wkb, Wvb);
    hipLaunchKernelGGL(convert_wout_kernel, dim3(48, 6), dim3(256), 0, stream, Wout, Woutb);
    hipLaunchKernelGGL(gemm_qkv, dim3(48, 7, 3), dim3(256), 0, stream,
                       xnb, Wqb, Wkb, Wvb, qt, kt, vt);
    hipLaunchKernelGGL(attn_kernel, dim3(BS * DCH, 2), dim3(256), 0, stream,
                       qt, kt, vt, probs, ot2);
    hipLaunchKernelGGL(gemm_wout, dim3(3, 7, 24), dim3(256), 0, stream, ot2, Woutb, partial);
    hipLaunchKernelGGL(reduce_out_kernel, dim3((ROWS * DCH + 255) / 256), dim3(256), 0, stream,
                       partial, xn, out);
}

// Round 12
// 128.803 us; speedup vs baseline: 1.4066x; 1.0391x over previous
//
#include <hip/hip_runtime.h>
#include <math.h>

#define BS 4
#define NTOK 196
#define DCH 384
#define HD 6144
#define ROWS (BS*NTOK)          // 784
#define MPAD 896                // 7*128
#define SCALE 0.05103103630798287f  // 1/sqrt(384)

typedef unsigned short u16;
typedef __attribute__((ext_vector_type(8))) short bf8v;      // 8 bf16 (4 VGPR)
typedef __attribute__((ext_vector_type(4))) float f4v;
typedef __attribute__((ext_vector_type(16))) float f16v;
typedef __attribute__((ext_vector_type(8))) unsigned short u16x8;
typedef __attribute__((ext_vector_type(4))) unsigned short u16x4;
typedef __attribute__((ext_vector_type(2))) unsigned int u32x2;

static __device__ __forceinline__ float b2f(u16 u) {
    unsigned int x = ((unsigned int)u) << 16;
    float f; __builtin_memcpy(&f, &x, 4); return f;
}
static __device__ __forceinline__ u16 f2b(float f) {
    unsigned int x; __builtin_memcpy(&x, &f, 4);
    unsigned int r = x + 0x7FFF + ((x >> 16) & 1);
    return (u16)(r >> 16);
}
static __device__ __forceinline__ unsigned int pack2(float lo, float hi) {
    unsigned int r;
    asm("v_cvt_pk_bf16_f32 %0, %1, %2" : "=v"(r) : "v"(lo), "v"(hi));
    return r;
}
static __device__ __forceinline__ float blo(unsigned int u) {
    unsigned int x = u << 16; float f; __builtin_memcpy(&f, &x, 4); return f;
}
static __device__ __forceinline__ float bhi(unsigned int u) {
    unsigned int x = u & 0xffff0000u; float f; __builtin_memcpy(&f, &x, 4); return f;
}

// ---------------------------------------------------------------- LayerNorm (bf16 out only, pad to 896)
__global__ __launch_bounds__(128) void ln_kernel(
    const float* __restrict__ x, const float* __restrict__ gamma,
    const float* __restrict__ beta, u16* __restrict__ xnb)
{
    int row = blockIdx.x;
    int t = threadIdx.x;
    if (row >= ROWS) {
        xnb[(size_t)row*DCH + t] = 0;
        xnb[(size_t)row*DCH + t + 128] = 0;
        xnb[(size_t)row*DCH + t + 256] = 0;
        return;
    }
    const float* xr = x + (size_t)row * DCH;
    float v0 = xr[t], v1 = xr[t + 128], v2 = xr[t + 256];
    float s  = v0 + v1 + v2;
    float ss = v0*v0 + v1*v1 + v2*v2;
    #pragma unroll
    for (int off = 1; off < 64; off <<= 1) {
        s  += __shfl_xor(s,  off);
        ss += __shfl_xor(ss, off);
    }
    __shared__ float red[4];
    int wv = t >> 6;
    if ((t & 63) == 0) { red[wv*2] = s; red[wv*2+1] = ss; }
    __syncthreads();
    float S = red[0] + red[2], SS = red[1] + red[3];
    float mu  = S * (1.0f / DCH);
    float var = SS * (1.0f / DCH) - mu * mu;
    float inv = rsqrtf(var + 1e-5f);
    u16* xb = xnb + (size_t)row * DCH;
    xb[t]       = f2b((v0 - mu) * inv * gamma[t]       + beta[t]);
    xb[t + 128] = f2b((v1 - mu) * inv * gamma[t + 128] + beta[t + 128]);
    xb[t + 256] = f2b((v2 - mu) * inv * gamma[t + 256] + beta[t + 256]);
}

// ------------------------------------------------- merged weight converts (flat grid)
// bid < 6912: W[384][6144] -> Wb[n'][k]; q,k: n' = dc*16+h; v: n' = n
// bid >= 6912: Wout[6144][384] -> Woutb[n][k], k = dc*16+h
__global__ __launch_bounds__(256) void convert_all_kernel(
    const float* __restrict__ Wq, const float* __restrict__ Wk, const float* __restrict__ Wv,
    const float* __restrict__ Wout,
    u16* __restrict__ Wqb, u16* __restrict__ Wkb, u16* __restrict__ Wvb,
    u16* __restrict__ Woutb)
{
    __shared__ u16 tbuf[32][33];
    __shared__ u16 tbuf2[128][65];
    int bid = blockIdx.x;
    int tid = threadIdx.x;
    if (bid < 6912) {
        int z = bid / 2304, rem = bid - z*2304;
        int k0 = (rem / 192) * 32, n0 = (rem % 192) * 32;
        const float* W = (z == 0) ? Wq : (z == 1) ? Wk : Wv;
        u16* Wb        = (z == 0) ? Wqb : (z == 1) ? Wkb : Wvb;
        #pragma unroll
        for (int it = 0; it < 4; it++) {
            int e = it*256 + tid; int kk = e >> 5, nn = e & 31;
            tbuf[kk][nn] = f2b(W[(size_t)(k0+kk)*HD + n0 + nn]);
        }
        __syncthreads();
        #pragma unroll
        for (int it = 0; it < 4; it++) {
            int e = it*256 + tid; int nn = e >> 5, kk = e & 31;
            int n_orig = n0 + nn;
            int np = (z == 2) ? n_orig : ((n_orig % DCH)*16 + n_orig / DCH);
            Wb[(size_t)np*DCH + k0 + kk] = tbuf[kk][nn];
        }
    } else {
        int b2 = bid - 6912;
        int dc0 = (b2 % 48) * 8;
        int n0  = (b2 / 48) * 64;
        #pragma unroll
        for (int it = 0; it < 32; it++) {
            int e = it*256 + tid; int r = e >> 6, c = e & 63;
            int h = r >> 3, d = r & 7;
            tbuf2[r][c] = f2b(Wout[(size_t)(h*DCH + dc0 + d)*DCH + n0 + c]);
        }
        __syncthreads();
        #pragma unroll
        for (int it = 0; it < 32; it++) {
            int e = it*256 + tid; int n = e >> 7, kk = e & 127;
            Woutb[(size_t)(n0+n)*HD + dc0*16 + kk] = tbuf2[(kk & 15)*8 + (kk >> 4)][n];
        }
    }
}

// ------------------------------------------------- MFMA proj GEMM (reg-staged) -> q/k [bd][i*16+h], v [bd][h][j]
__global__ __launch_bounds__(256) void gemm_qkv(
    const u16* __restrict__ xnb,
    const u16* __restrict__ Wqb, const u16* __restrict__ Wkb, const u16* __restrict__ Wvb,
    u16* __restrict__ qt, u16* __restrict__ kt, u16* __restrict__ vt)
{
    const u16* Wb = (blockIdx.z == 0) ? Wqb : (blockIdx.z == 1) ? Wkb : Wvb;
    u16* C        = (blockIdx.z == 0) ? qt : (blockIdx.z == 1) ? kt : vt;
    __shared__ u16 As[128*64];
    __shared__ u16 Bs[128*64];
    int tid = threadIdx.x, lane = tid & 63, wv = tid >> 6;
    int wm = wv >> 1, wn = wv & 1;
    int row0 = blockIdx.y * 128, col0 = blockIdx.x * 128;
    f4v acc[4][4] = {};
    int rsub = tid >> 3;
    int g8 = tid & 7;
    int g8s = g8 ^ (rsub & 7);

    for (int k0 = 0; k0 < 384; k0 += 64) {
        u16x8 ra[4], rb[4];
        #pragma unroll
        for (int c = 0; c < 4; c++) {
            int row = c*32 + rsub;
            ra[c] = *(const u16x8*)(xnb + (size_t)(row0+row)*DCH + k0 + g8*8);
            rb[c] = *(const u16x8*)(Wb  + (size_t)(col0+row)*DCH + k0 + g8*8);
        }
        __syncthreads();
        #pragma unroll
        for (int c = 0; c < 4; c++) {
            int row = c*32 + rsub;
            *(u16x8*)&As[row*64 + g8s*8] = ra[c];
            *(u16x8*)&Bs[row*64 + g8s*8] = rb[c];
        }
        __syncthreads();
        #pragma unroll
        for (int ks = 0; ks < 2; ks++) {
            int gr = (ks*4 + (lane >> 4)) ^ (lane & 7);
            bf8v af[4], bf[4];
            #pragma unroll
            for (int m = 0; m < 4; m++)
                af[m] = *(const bf8v*)&As[(wm*64 + m*16 + (lane & 15))*64 + gr*8];
            #pragma unroll
            for (int n = 0; n < 4; n++)
                bf[n] = *(const bf8v*)&Bs[(wn*64 + n*16 + (lane & 15))*64 + gr*8];
            #pragma unroll
            for (int m = 0; m < 4; m++)
                #pragma unroll
                for (int n = 0; n < 4; n++)
                    acc[m][n] = __builtin_amdgcn_mfma_f32_16x16x32_bf16(af[m], bf[n], acc[m][n], 0, 0, 0);
        }
    }
    int cb = lane & 15, rg = lane >> 4;
    #pragma unroll
    for (int m = 0; m < 4; m++) {
        int r0 = row0 + wm*64 + m*16 + rg*4;
        if (r0 >= ROWS) continue;
        int b = r0 / NTOK, i = r0 - b*NTOK;
        #pragma unroll
        for (int n = 0; n < 4; n++) {
            int nb = col0 + wn*64 + n*16;
            if (blockIdx.z == 2) {
                int ncol = nb + cb;
                int h = ncol / DCH, dc = ncol - h*DCH;
                size_t addr = ((size_t)((b*DCH + dc)*16 + h))*NTOK + i;
                u16x4 o = {f2b(acc[m][n][0]), f2b(acc[m][n][1]), f2b(acc[m][n][2]), f2b(acc[m][n][3])};
                *(u16x4*)(C + addr) = o;
            } else {
                int dc = nb >> 4;
                size_t a2 = ((size_t)(b*DCH + dc))*(NTOK*16) + (size_t)i*16 + cb;
                C[a2]      = f2b(acc[m][n][0]);   // lanes cb=0..15: 32B dense
                C[a2 + 16] = f2b(acc[m][n][1]);
                C[a2 + 32] = f2b(acc[m][n][2]);
                C[a2 + 48] = f2b(acc[m][n][3]);
            }
        }
    }
}

// ------------------------------------------------- MFMA attention v6 (1 block per bd, 7 waves)
__global__ __launch_bounds__(448) void attn_kernel(
    const u16* __restrict__ qt, const u16* __restrict__ kt, const u16* __restrict__ vt,
    float* __restrict__ probs, u16* __restrict__ ot2)
{
    __shared__ u16 Klds[NTOK*16];        // [j][h], linear
    __shared__ u16 Vlds[NTOK*16 + 16];   // [h][j], +pad for tail b64 reads
    __shared__ u16 Plds[7][2048];        // per-wave 32x64 bf16, swizzled
    __shared__ float invs[7][32];        // per-wave row normalizers
    int bd = blockIdx.x;
    int b = bd / DCH, dc = bd - b*DCH;
    int tid = threadIdx.x;
    int wv = tid >> 6;                   // wave = i-tile 0..6
    int it = wv;
    int lane = tid & 63;
    int l31 = lane & 31, hi = lane >> 5;
    const u16* qb = qt + (size_t)bd * (NTOK*16);
    const u16* kb = kt + (size_t)bd * (NTOK*16);
    const u16* vb = vt + (size_t)bd * (NTOK*16);

    // stage K and V once per bd (coalesced, single iteration for tid<392)
    for (int e8 = tid; e8 < (NTOK*16)/8; e8 += 448) {
        *(u16x8*)&Klds[e8*8] = *(const u16x8*)(kb + e8*8);
        *(u16x8*)&Vlds[e8*8] = *(const u16x8*)(vb + e8*8);
    }
    __syncthreads();
    u16* Pw = Plds[wv];

    int iq = it*32 + l31;
    int iqc = iq < NTOK ? iq : NTOK-1;
    bf8v qf = *(const bf8v*)(qb + iqc*16 + hi*8);

    unsigned int P[6][8];     // 6 j-tiles x 16 bf16 (unnormalized exp), static-indexed
    float et[4];              // jt=6 tail (valid on hi==0)
    float s0 = 0.f, s1 = 0.f, s2 = 0.f, s3 = 0.f;

    #pragma unroll
    for (int jt = 0; jt < 7; jt++) {
        int j = jt*32 + l31;
        int jc = j < NTOK ? j : NTOK-1;
        bf8v kf = *(const bf8v*)&Klds[jc*16 + hi*8];
        f16v z = {};
        f16v Sv = __builtin_amdgcn_mfma_f32_32x32x16_bf16(kf, qf, z, 0, 0, 0);
        if (jt < 6) {
            float e[16];
            #pragma unroll
            for (int r = 0; r < 16; r++) e[r] = __expf(Sv[r] * SCALE);
            #pragma unroll
            for (int r = 0; r < 16; r += 4) {
                s0 += e[r]; s1 += e[r+1]; s2 += e[r+2]; s3 += e[r+3];
            }
            #pragma unroll
            for (int g = 0; g < 4; g++) {
                P[jt][2*g]   = pack2(e[4*g],   e[4*g+1]);
                P[jt][2*g+1] = pack2(e[4*g+2], e[4*g+3]);
            }
        } else {
            #pragma unroll
            for (int r = 0; r < 4; r++)
                et[r] = (hi == 0) ? __expf(Sv[r] * SCALE) : 0.f;
            s0 += et[0]; s1 += et[1]; s2 += et[2]; s3 += et[3];
        }
    }
    float Sig = (s0 + s1) + (s2 + s3);
    Sig += __shfl_xor(Sig, 32);          // combine the row's two halves
    float inv = 1.0f / Sig;              // per-row (row = l31) normalizer
    if (hi == 0) invs[wv][l31] = inv;    // same-wave LDS broadcast (lgkmcnt-ordered)

    float* prow_base = probs + (size_t)bd * NTOK * NTOK;
    f16v O = {};
    int row_lo = lane >> 4;      // 0..3 (probs store sublane)
    int scol   = lane & 15;      // 8B-chunk / 4-float column

    #pragma unroll
    for (int jtp = 0; jtp < 3; jtp++) {
        // ---- write this 64-j slab into the swizzled LDS tile (raw packed bf16)
        #pragma unroll
        for (int jtl = 0; jtl < 2; jtl++) {
            int jt = jtp*2 + jtl;
            #pragma unroll
            for (int g = 0; g < 4; g++) {
                int cs  = jtl*8 + 2*g + hi;              // 8B chunk 0..15
                int csw = cs ^ ((l31 & 7) << 1);         // even-mask XOR keeps 16B pairing
                u32x2 w2 = {P[jt][2*g], P[jt][2*g+1]};
                *(u32x2*)&Pw[l31*64 + csw*4] = w2;
            }
        }
        // ---- coalesced probs stores: 4 rows x 64 consecutive floats per instr
        #pragma unroll
        for (int rr = 0; rr < 8; rr++) {
            int row = rr*4 + row_lo;
            float rinv = invs[wv][row];                  // LDS broadcast read
            int csw = scol ^ ((row & 7) << 1);
            u32x2 pv = *(const u32x2*)&Pw[row*64 + csw*4];
            int gi = it*32 + row;
            if (gi < NTOK) {
                f4v o = {blo(pv.x)*rinv, bhi(pv.x)*rinv, blo(pv.y)*rinv, bhi(pv.y)*rinv};
                *(f4v*)(prow_base + (size_t)gi*NTOK + jtp*64 + scol*4) = o;
            }
        }
        // ---- PV: A-frag = straight b128 read from the tile (row=l31, 8 consecutive j)
        #pragma unroll
        for (int jtl = 0; jtl < 2; jtl++) {
            #pragma unroll
            for (int u = 0; u < 2; u++) {
                int m  = jtl*4 + u*2 + hi;               // 16B chunk 0..7
                int mw = m ^ (l31 & 7);
                bf8v pf = *(const bf8v*)&Pw[l31*64 + mw*8];
                int j0 = jtp*64 + jtl*32 + u*16 + hi*8;
                int off = (l31 & 15)*NTOK + j0;
                u16x4 vlo = *(const u16x4*)&Vlds[off];
                u16x4 vh4 = *(const u16x4*)&Vlds[off + 4];
                u16 varr[8];
                #pragma unroll
                for (int e = 0; e < 4; e++) { varr[e] = vlo[e]; varr[4+e] = vh4[e]; }
                bf8v vf; __builtin_memcpy(&vf, varr, 16);
                O = __builtin_amdgcn_mfma_f32_32x32x16_bf16(pf, vf, O, 0, 0, 0);
            }
        }
    }

    // ---- tail jt=6 (j 192..195): probs + PV (frag is lane-local, no shfl)
    if (hi == 0 && iq < NTOK) {
        f4v o = {et[0]*inv, et[1]*inv, et[2]*inv, et[3]*inv};
        *(f4v*)(prow_base + (size_t)iq*NTOK + 192) = o;
    }
    {
        u16 arr[8];
        #pragma unroll
        for (int e = 0; e < 4; e++) {
            arr[e]   = (hi == 0) ? f2b(et[e]) : (u16)0;
            arr[4+e] = 0;
        }
        bf8v pf; __builtin_memcpy(&pf, arr, 16);
        int j0 = 192 + hi*8;
        int off = (l31 & 15)*NTOK + j0;    // hi=1 reads into pad (P=0) — benign
        u16x4 vlo = *(const u16x4*)&Vlds[off];
        u16x4 vh4 = *(const u16x4*)&Vlds[off + 4];
        u16 varr[8];
        #pragma unroll
        for (int e = 0; e < 4; e++) { varr[e] = vlo[e]; varr[4+e] = vh4[e]; }
        bf8v vf; __builtin_memcpy(&vf, varr, 16);
        O = __builtin_amdgcn_mfma_f32_32x32x16_bf16(pf, vf, O, 0, 0, 0);
    }

    // ---- scale O by each row's inv (LDS broadcast per D-row)
    if (l31 < 16) {
        #pragma unroll
        for (int r = 0; r < 16; r++) {
            int il = (r & 3) + 8*(r >> 2) + 4*hi;
            int i = it*32 + il;
            if (i < NTOK) {
                float iv = invs[wv][il];
                ot2[((size_t)(b*NTOK + i))*HD + dc*16 + l31] = f2b(O[r] * iv);
            }
        }
    }
}

// ------------------------------------------------- MFMA out-proj (reg-staged), split-K 24
__global__ __launch_bounds__(256) void gemm_wout(
    const u16* __restrict__ A, const u16* __restrict__ Bw, float* __restrict__ partial)
{
    __shared__ u16 As[128*64];
    __shared__ u16 Bs[128*64];
    int tid = threadIdx.x, lane = tid & 63, wv = tid >> 6;
    int wm = wv >> 1, wn = wv & 1;
    int row0 = blockIdx.y * 128, col0 = blockIdx.x * 128;
    int kbase = blockIdx.z * 256;
    f4v acc[4][4] = {};
    int rsub = tid >> 3;
    int g8 = tid & 7;
    int g8s = g8 ^ (rsub & 7);

    for (int k0 = kbase; k0 < kbase + 256; k0 += 64) {
        u16x8 ra[4], rb[4];
        #pragma unroll
        for (int c = 0; c < 4; c++) {
            int row = c*32 + rsub;
            int arow = row0 + row; if (arow > ROWS-1) arow = ROWS-1;   // clamp (masked at store)
            ra[c] = *(const u16x8*)(A  + (size_t)arow*HD + k0 + g8*8);
            rb[c] = *(const u16x8*)(Bw + (size_t)(col0+row)*HD + k0 + g8*8);
        }
        __syncthreads();
        #pragma unroll
        for (int c = 0; c < 4; c++) {
            int row = c*32 + rsub;
            *(u16x8*)&As[row*64 + g8s*8] = ra[c];
            *(u16x8*)&Bs[row*64 + g8s*8] = rb[c];
        }
        __syncthreads();
        #pragma unroll
        for (int ks = 0; ks < 2; ks++) {
            int gr = (ks*4 + (lane >> 4)) ^ (lane & 7);
            bf8v af[4], bf[4];
            #pragma unroll
            for (int m = 0; m < 4; m++)
                af[m] = *(const bf8v*)&As[(wm*64 + m*16 + (lane & 15))*64 + gr*8];
            #pragma unroll
            for (int n = 0; n < 4; n++)
                bf[n] = *(const bf8v*)&Bs[(wn*64 + n*16 + (lane & 15))*64 + gr*8];
            #pragma unroll
            for (int m = 0; m < 4; m++)
                #pragma unroll
                for (int n = 0; n < 4; n++)
                    acc[m][n] = __builtin_amdgcn_mfma_f32_16x16x32_bf16(af[m], bf[n], acc[m][n], 0, 0, 0);
        }
    }
    float* Pp = partial + (size_t)blockIdx.z * ROWS * DCH;
    int cb = lane & 15, rg = lane >> 4;
    #pragma unroll
    for (int m = 0; m < 4; m++) {
        int r0 = row0 + wm*64 + m*16 + rg*4;
        #pragma unroll
        for (int n = 0; n < 4; n++) {
            int ncol = col0 + wn*64 + n*16 + cb;
            #pragma unroll
            for (int j = 0; j < 4; j++) {
                int r = r0 + j;
                if (r < ROWS) Pp[(size_t)r*DCH + ncol] = acc[m][n][j];
            }
        }
    }
}

// ------------------------------------------------- split-K reduce + bf16 residual
__global__ __launch_bounds__(256) void reduce_out_kernel(
    const float* __restrict__ partial, const u16* __restrict__ xnb, float* __restrict__ out)
{
    int e = blockIdx.x * 256 + threadIdx.x;
    if (e < ROWS * DCH) {
        float s = b2f(xnb[e]);
        #pragma unroll
        for (int c = 0; c < 24; c++)
            s += partial[(size_t)c * ROWS * DCH + e];
        out[e] = s;
    }
}

extern "C" void kernel_launch(void* const* d_in, const int* in_sizes, int n_in,
                              void* d_out, int out_size, void* d_ws, size_t ws_size,
                              hipStream_t stream) {
    (void)in_sizes; (void)n_in; (void)out_size; (void)ws_size;
    const float* x     = (const float*)d_in[0];
    const float* Wq    = (const float*)d_in[1];
    const float* Wk    = (const float*)d_in[2];
    const float* Wv    = (const float*)d_in[3];
    const float* Wout  = (const float*)d_in[4];
    const float* gamma = (const float*)d_in[5];
    const float* beta  = (const float*)d_in[6];

    float* out   = (float*)d_out;
    float* probs = out + (size_t)ROWS * DCH;

    char* w = (char*)d_ws;
    u16* xnb   = (u16*)w;    w += (size_t)MPAD*DCH*2;
    u16* Wqb   = (u16*)w;    w += (size_t)HD*DCH*2;
    u16* Wkb   = (u16*)w;    w += (size_t)HD*DCH*2;
    u16* Wvb   = (u16*)w;    w += (size_t)HD*DCH*2;
    u16* Woutb = (u16*)w;    w += (size_t)DCH*HD*2;
    u16* qt    = (u16*)w;    w += (size_t)ROWS*HD*2;
    u16* kt    = (u16*)w;    w += (size_t)ROWS*HD*2;
    u16* vt    = (u16*)w;    w += (size_t)ROWS*HD*2;
    u16* ot2   = (u16*)w;    w += (size_t)ROWS*HD*2;
    float* partial = (float*)qt;   // 24*1.2MB = 28.9MB spans qt+kt+vt (all dead after attn)

    hipLaunchKernelGGL(ln_kernel, dim3(MPAD), dim3(128), 0, stream, x, gamma, beta, xnb);
    hipLaunchKernelGGL(convert_all_kernel, dim3(7200), dim3(256), 0, stream,
                       Wq, Wk, Wv, Wout, Wqb, Wkb, Wvb, Woutb);
    hipLaunchKernelGGL(gemm_qkv, dim3(48, 7, 3), dim3(256), 0, stream,
                       xnb, Wqb, Wkb, Wvb, qt, kt, vt);
    hipLaunchKernelGGL(attn_kernel, dim3(BS * DCH), dim3(448), 0, stream,
                       qt, kt, vt, probs, ot2);
    hipLaunchKernelGGL(gemm_wout, dim3(3, 7, 24), dim3(256), 0, stream, ot2, Woutb, partial);
    hipLaunchKernelGGL(reduce_out_kernel, dim3((ROWS * DCH + 255) / 256), dim3(256), 0, stream,
                       partial, xnb, out);
}